// Round 22
// baseline (42.966 us; speedup 1.0000x reference)
//
#include <hip/hip_runtime.h>
#include <math.h>

#define C2 2.8853900817779268f   // 2*log2(e)

// 256 blocks x 512 thr (8 waves x 4 q rows), 1 block/CU, 160 KB LDS.
// r18 structure + explicitly software-pipelined score loop: operand sets A/B
// alternate; each set's 9 LDS loads are issued one full compute block (~120
// VALU cyc) before use, covering LDS return latency at 2 waves/SIMD.
__global__ __launch_bounds__(512) void addattn_kernel(
    const float* __restrict__ q_g, const float* __restrict__ k_g,
    const float* __restrict__ v_g, const float* __restrict__ w_g,
    float* __restrict__ out)
{
    __shared__ float kbuf[32768];   // 128 KB: Ek[t4][g32][rot64][hi4]
    __shared__ float sB[8192];      //  32 KB: 8 waves x 1024f strip (Eq[4][128]|w -> attn[4][256])

    const int tid  = threadIdx.x;
    const int lane = tid & 63;
    const int wv   = __builtin_amdgcn_readfirstlane(tid >> 6);  // 0..7 uniform

    // XCD-grouped remap: XCD x serves batches 4x..4x+3 (K/V/Q L2-resident)
    const int xcd = blockIdx.x & 7;
    const int sub = blockIdx.x >> 3;          // 0..31
    const int b   = (xcd << 2) + (sub >> 3);
    const int qr0 = ((sub & 7) << 5) + (wv << 2);   // wave's 4 q rows

    float* strip = sB + (wv << 10);   // 1024 floats, wave-private

    // ---- strip: w copy at [512..640), Eq[4][128] at [0..512) (r18 layout) ----
    if (lane < 32) *(float4*)&strip[512 + (lane << 2)] = ((const float4*)w_g)[lane];
    {
        const float* qb = q_g + (size_t)(b * 256 + qr0) * 128;
        #pragma unroll
        for (int j = 0; j < 2; ++j) {
            int f = lane + (j << 6);
            int r = f >> 5, c = f & 31;
            float4 qv = *(const float4*)(qb + (r << 7) + (c << 2));
            float4 E;
            E.x = __builtin_amdgcn_exp2f(C2 * qv.x);
            E.y = __builtin_amdgcn_exp2f(C2 * qv.y);
            E.z = __builtin_amdgcn_exp2f(C2 * qv.z);
            E.w = __builtin_amdgcn_exp2f(C2 * qv.w);
            *(float4*)&strip[(r << 7) + (c << 2)] = E;
        }
    }

    // ---- stage K[b]: load -> exp2 -> rotation-swizzled kbuf (conflict-free) ----
    {
        const float4* kg4 = (const float4*)(k_g + (size_t)b * 32768);
        #pragma unroll
        for (int j = 0; j < 16; ++j) {
            int f = tid + (j << 9);            // 0..8191 float4s
            float4 kv = kg4[f];
            int k = f >> 5, g = f & 31;
            float4 E;
            E.x = __builtin_amdgcn_exp2f(C2 * kv.x);
            E.y = __builtin_amdgcn_exp2f(C2 * kv.y);
            E.z = __builtin_amdgcn_exp2f(C2 * kv.z);
            E.w = __builtin_amdgcn_exp2f(C2 * kv.w);
            int rot = ((k & 63) + g) & 63;
            *(float4*)&kbuf[((k >> 6) << 13) + (g << 8) + (rot << 2)] = E;
        }
    }
    __syncthreads();    // the only barrier

    // ---- score: software-pipelined A/B over g = 0..31 ----
    float s[4][4];
    #pragma unroll
    for (int t = 0; t < 4; ++t)
        #pragma unroll
        for (int r = 0; r < 4; ++r) s[t][r] = 0.f;

    #define LOADSET(G, W, E0, E1, E2, E3, K0, K1, K2, K3)                      \
    {                                                                          \
        const int g_ = (G);                                                    \
        W  = *(const float4*)&strip[512 + (g_ << 2)];                          \
        E0 = *(const float4*)&strip[g_ << 2];                                  \
        E1 = *(const float4*)&strip[128 + (g_ << 2)];                          \
        E2 = *(const float4*)&strip[256 + (g_ << 2)];                          \
        E3 = *(const float4*)&strip[384 + (g_ << 2)];                          \
        const int rot_ = (((lane + g_) & 63) << 2) + (g_ << 8);                \
        K0 = *(const float4*)&kbuf[rot_];                                      \
        K1 = *(const float4*)&kbuf[8192 + rot_];                               \
        K2 = *(const float4*)&kbuf[16384 + rot_];                              \
        K3 = *(const float4*)&kbuf[24576 + rot_];                              \
    }

    #define RB(E, K4, S)                                                       \
    {                                                                          \
        float d0 = fmaf(E.x, K4.x, 1.f), d1 = fmaf(E.y, K4.y, 1.f);            \
        float d2 = fmaf(E.z, K4.z, 1.f), d3 = fmaf(E.w, K4.w, 1.f);            \
        float P01 = d0 * d1, P23 = d2 * d3;                                    \
        float N01 = fmaf(W_.x, d1, W_.y * d0);                                 \
        float N23 = fmaf(W_.z, d3, W_.w * d2);                                 \
        float num = fmaf(N01, P23, N23 * P01);                                 \
        S = fmaf(num, __builtin_amdgcn_rcpf(P01 * P23), S);                    \
    }
    #define COMPUTE(W, E0, E1, E2, E3, K0, K1, K2, K3)                         \
    {                                                                          \
        float4 W_ = W;                                                         \
        RB(E0, K0, s[0][0]) RB(E1, K0, s[0][1]) RB(E2, K0, s[0][2]) RB(E3, K0, s[0][3]) \
        RB(E0, K1, s[1][0]) RB(E1, K1, s[1][1]) RB(E2, K1, s[1][2]) RB(E3, K1, s[1][3]) \
        RB(E0, K2, s[2][0]) RB(E1, K2, s[2][1]) RB(E2, K2, s[2][2]) RB(E3, K2, s[2][3]) \
        RB(E0, K3, s[3][0]) RB(E1, K3, s[3][1]) RB(E2, K3, s[3][2]) RB(E3, K3, s[3][3]) \
    }

    {
        float4 wA, e0A, e1A, e2A, e3A, k0A, k1A, k2A, k3A;
        float4 wB, e0B, e1B, e2B, e3B, k0B, k1B, k2B, k3B;
        LOADSET(0, wA, e0A, e1A, e2A, e3A, k0A, k1A, k2A, k3A)
        #pragma unroll 1
        for (int gp = 0; gp < 16; ++gp) {
            const int g0 = gp << 1;
            LOADSET(g0 + 1, wB, e0B, e1B, e2B, e3B, k0B, k1B, k2B, k3B)
            COMPUTE(wA, e0A, e1A, e2A, e3A, k0A, k1A, k2A, k3A)
            if (gp < 15)
                LOADSET(g0 + 2, wA, e0A, e1A, e2A, e3A, k0A, k1A, k2A, k3A)
            COMPUTE(wB, e0B, e1B, e2B, e3B, k0B, k1B, k2B, k3B)
        }
    }
    #undef COMPUTE
    #undef RB
    #undef LOADSET

    // ---- softmax per row (lane holds k = 64t+lane); attn overlays strip ----
    #pragma unroll
    for (int r = 0; r < 4; ++r) {
        float x0 = -C2 * s[0][r], x1 = -C2 * s[1][r];
        float x2 = -C2 * s[2][r], x3 = -C2 * s[3][r];
        float m = fmaxf(fmaxf(x0, x1), fmaxf(x2, x3));
        #pragma unroll
        for (int off = 32; off; off >>= 1) m = fmaxf(m, __shfl_xor(m, off));
        float e0 = __builtin_amdgcn_exp2f(x0 - m);
        float e1 = __builtin_amdgcn_exp2f(x1 - m);
        float e2 = __builtin_amdgcn_exp2f(x2 - m);
        float e3 = __builtin_amdgcn_exp2f(x3 - m);
        float sum = (e0 + e1) + (e2 + e3);
        #pragma unroll
        for (int off = 32; off; off >>= 1) sum += __shfl_xor(sum, off);
        float inv = __builtin_amdgcn_rcpf(sum);
        strip[(r << 8) + lane]       = e0 * inv;   // own-wave ds ordering
        strip[(r << 8) + 64 + lane]  = e1 * inv;
        strip[(r << 8) + 128 + lane] = e2 * inv;
        strip[(r << 8) + 192 + lane] = e3 * inv;
    }

    // ---- PV: lane = h-pair (h = 2*lane, 2*lane+1); V f32 global (L1/L2-hot) ----
    float2 o0, o1, o2, o3;
    o0.x = o0.y = o1.x = o1.y = 0.f;
    o2.x = o2.y = o3.x = o3.y = 0.f;
    const float2* vp = (const float2*)(v_g + (size_t)b * 32768) + lane;
    #pragma unroll 4
    for (int j4 = 0; j4 < 64; ++j4) {
        float4 a0 = *(const float4*)(strip + (j4 << 2));          // row bcasts
        float4 a1 = *(const float4*)(strip + 256 + (j4 << 2));
        float4 a2 = *(const float4*)(strip + 512 + (j4 << 2));
        float4 a3 = *(const float4*)(strip + 768 + (j4 << 2));
        #pragma unroll
        for (int i = 0; i < 4; ++i) {
            float2 v2 = vp[((j4 << 2) + i) << 6];                 // 512B coalesced
            float c0 = (&a0.x)[i], c1 = (&a1.x)[i], c2 = (&a2.x)[i], c3 = (&a3.x)[i];
            o0.x = fmaf(c0, v2.x, o0.x); o0.y = fmaf(c0, v2.y, o0.y);
            o1.x = fmaf(c1, v2.x, o1.x); o1.y = fmaf(c1, v2.y, o1.y);
            o2.x = fmaf(c2, v2.x, o2.x); o2.y = fmaf(c2, v2.y, o2.y);
            o3.x = fmaf(c3, v2.x, o3.x); o3.y = fmaf(c3, v2.y, o3.y);
        }
    }

    float* ob = out + (size_t)(b * 256 + qr0) * 128 + (lane << 1);
    *(float2*)(ob)       = o0;
    *(float2*)(ob + 128) = o1;
    *(float2*)(ob + 256) = o2;
    *(float2*)(ob + 384) = o3;
}

extern "C" void kernel_launch(void* const* d_in, const int* in_sizes, int n_in,
                              void* d_out, int out_size, void* d_ws, size_t ws_size,
                              hipStream_t stream) {
    const float* q = (const float*)d_in[0];
    const float* k = (const float*)d_in[1];
    const float* v = (const float*)d_in[2];
    const float* w = (const float*)d_in[3];
    float* out = (float*)d_out;
    addattn_kernel<<<256, 512, 0, stream>>>(q, k, v, w, out);
}